// Round 4
// baseline (2888.669 us; speedup 1.0000x reference)
//
#include <hip/hip_runtime.h>

#define B_ 64
#define T_ 512
#define D_ 1024
#define H_ 1024

typedef _Float16 half8 __attribute__((ext_vector_type(8)));
typedef float floatx16 __attribute__((ext_vector_type(16)));

__device__ __forceinline__ float sigm(float x)   { return 1.f / (1.f + __expf(-x)); }
__device__ __forceinline__ float tanh_f(float x) { return 1.f - 2.f / (1.f + __expf(2.f * x)); }

// ---------------- prep: inputs fp32 -> f16 (8 elems / thread) ----------------
__global__ void k_prep_x(const float* __restrict__ x, _Float16* __restrict__ xf) {
  int i = blockIdx.x * blockDim.x + threadIdx.x;   // 0 .. 4194303
  const float4* p = (const float4*)x + (size_t)i * 2;
  float4 a = p[0], b = p[1];
  half8 v;
  v[0]=(_Float16)a.x; v[1]=(_Float16)a.y; v[2]=(_Float16)a.z; v[3]=(_Float16)a.w;
  v[4]=(_Float16)b.x; v[5]=(_Float16)b.y; v[6]=(_Float16)b.z; v[7]=(_Float16)b.w;
  ((half8*)xf)[i] = v;
}

// ---------------- prep: hb1 = ~bits(f16(init_h)) (gen-1 tagged), hb0 = 0xFFFF sentinel ----
// hb0 sentinel (bit14=1) is the BASE CASE of the tag induction: step-1 readers
// expect tag=0 and so can never accept uninitialized/previous-run content.
__global__ void k_prep_misc(const float* __restrict__ init_h,
                            unsigned short* __restrict__ hb0,
                            unsigned short* __restrict__ hb1) {
  int i = blockIdx.x * blockDim.x + threadIdx.x;   // grid 256x256 = 65536
  union { _Float16 h; unsigned short u; } cv;
  cv.h = (_Float16)init_h[i];
  hb1[i] = (unsigned short)~cv.u;
  hb0[i] = 0xFFFFu;
}

// ---------------- persistent LSTM kernel ----------------
// 256 WGs (1/CU), 256 threads (4 waves). WG w: batch-half bh=w>>7, col-chunk jc=w&127
// (8 hidden cols -> 32 z-cols {gate*H + jc*8+jj}).
//
// SELF-CERTIFYING h exchange (no flags, no fences, no acks):
//   |h| <= 1 mathematically -> f16 bit14 == 0 always. Write-generation g=(s>>1)&1:
//   g=0 stores raw bits, g=1 stores ~bits (bit14==1, exact value via ~).
//   Producers: one relaxed AGENT atomic u64 store per 4 cols (tear-free unit).
//   Consumers: relaxed AGENT atomic u64 loads; retry any element whose bit14
//   != expected generation. Per-address LLC serialization makes generations
//   monotone; hb0's 0xFFFF init + hb1's ~init provide the induction base case,
//   so 2 buffers x 2 gens is race-free within and across runs.
//   Consumers unblock per-u64 as producer THREADS land - no WG-level coupling.
template <bool XF16>
__launch_bounds__(256, 1)
__global__ void k_lstm(const float* __restrict__ x32, const _Float16* __restrict__ xf,
                       const int* __restrict__ lengths, const float* __restrict__ init_c,
                       const float* __restrict__ Wi, const float* __restrict__ Wh,
                       const float* __restrict__ bias,
                       _Float16* __restrict__ hb0, _Float16* __restrict__ hb1,
                       float* __restrict__ out, float* __restrict__ finc,
                       float* __restrict__ finh)
{
  __shared__ _Float16 slab[32768];       // 64 KB: Wh slice, B-frag order
  __shared__ _Float16 hlds[32][1028];    // 64.3 KB: staged h, +4 halfs pad (2-way banks)
  __shared__ float red[4][32][40];       // 20 KB: wave partials, stride 40

  const int w    = blockIdx.x;
  const int bh   = w >> 7;
  const int jc   = w & 127;
  const int t    = threadIdx.x;
  const int wave = t >> 6;
  const int lane = t & 63;
  const int m    = lane & 31;
  const int kh   = lane >> 5;

  const int gate = m >> 3;
  const int col  = gate * H_ + jc * 8 + (m & 7);

  // ---- one-time: Wh slice -> LDS slab (f16, B-fragment order, kb = k/16) ----
  for (int kbb = 0; kbb < 16; ++kbb) {
    const int kb = kbb * 4 + wave;
    const int kc = kb * 16 + kh * 8;
    half8 v;
    #pragma unroll
    for (int j = 0; j < 8; ++j)
      v[j] = (_Float16)Wh[(size_t)(kc + j) * 4096 + col];
    *(half8*)&slab[kb * 512 + lane * 8] = v;
  }

  // ---- one-time: Wi slice -> 64 permanent VGPRs (B-fragment order) ----
  half8 wia[16];
  #pragma unroll
  for (int i = 0; i < 16; ++i) {
    const int kc = (wave * 16 + i) * 16 + kh * 8;
    half8 v;
    #pragma unroll
    for (int j = 0; j < 8; ++j)
      v[j] = (_Float16)Wi[(size_t)(kc + j) * 4096 + col];
    wia[i] = v;
  }

  // ---- per-thread gate-phase ids: one (batch, hidden-col) pair ----
  const int bl = t >> 3, jj = t & 7;
  const int bG = bh * 32 + bl;
  const int jG = jc * 8 + jj;
  float c = init_c[bG * H_ + jG];
  const int len = lengths[bG];
  const float bz0 = bias[0 * H_ + jG];
  const float bz1 = bias[1 * H_ + jG];
  const float bz2 = bias[2 * H_ + jG];
  const float bz3 = bias[3 * H_ + jG];

  const int bA = bh * 32 + m;                         // A-fragment row (batch)
  const _Float16* xbase   = XF16 ? (xf + (size_t)bA * T_ * D_ + kh * 8) : (const _Float16*)0;
  const float*    xbase32 = x32 + (size_t)bA * T_ * D_ + kh * 8;

  __syncthreads();

  // ---- x fragment registers, prefetched one step ahead (64 VGPRs) ----
  half8 xa[16];
  if (XF16) {
    const _Float16* xs = xbase;   // s = 0
    #pragma unroll
    for (int i = 0; i < 16; ++i)
      xa[i] = *(const half8*)(xs + (wave * 16 + i) * 16);
  }

  for (int s = 0; s < T_; ++s) {
    const int eg = (s == 0) ? 1 : (((s - 1) >> 1) & 1);   // expected producer generation

    // ---- issue coalesced h staging loads (self-certifying data, no flag poll) ----
    const _Float16* hsrc = (s & 1) ? hb0 : hb1;   // buffer written at step s-1
    unsigned long long* hq =
        (unsigned long long*)hsrc + (size_t)bh * 8192;   // bh*32*1024 halfs / 4
    unsigned long long q[32];
    #pragma unroll
    for (int r = 0; r < 32; ++r)
      q[r] = __hip_atomic_load(hq + r * 256 + wave * 64 + lane,
                               __ATOMIC_RELAXED, __HIP_MEMORY_SCOPE_AGENT);

    // ---- x phase (pure-register MFMA; overlaps the staging-load latency) ----
    floatx16 C;
    #pragma unroll
    for (int r = 0; r < 16; ++r) C[r] = 0.f;
    if (XF16) {
      #pragma unroll
      for (int i = 0; i < 16; ++i)
        C = __builtin_amdgcn_mfma_f32_32x32x16_f16(xa[i], wia[i], C, 0, 0, 0);
    } else {
      const float* xs = xbase32 + (size_t)s * D_;
      #pragma unroll
      for (int i = 0; i < 16; ++i) {
        const float4* p = (const float4*)(xs + (wave * 16 + i) * 16);
        float4 u0 = p[0], u1 = p[1];
        half8 v;
        v[0]=(_Float16)u0.x; v[1]=(_Float16)u0.y; v[2]=(_Float16)u0.z; v[3]=(_Float16)u0.w;
        v[4]=(_Float16)u1.x; v[5]=(_Float16)u1.y; v[6]=(_Float16)u1.z; v[7]=(_Float16)u1.w;
        C = __builtin_amdgcn_mfma_f32_32x32x16_f16(v, wia[i], C, 0, 0, 0);
      }
    }

    // ---- verify freshness: bit14 of every u64 must equal eg; retry stale ones ----
    {
      int spin = 0;
      while (true) {
        bool all = true;
        #pragma unroll
        for (int r = 0; r < 32; ++r) {
          if ((int)((q[r] >> 14) & 1ull) != eg) {
            q[r] = __hip_atomic_load(hq + r * 256 + wave * 64 + lane,
                                     __ATOMIC_RELAXED, __HIP_MEMORY_SCOPE_AGENT);
            all = false;
          }
        }
        if (all) break;
        __builtin_amdgcn_s_sleep(1);
        if (++spin > (1 << 21)) break;   // safety valve against deadlock-hang
      }
      if (eg) {
        #pragma unroll
        for (int r = 0; r < 32; ++r) q[r] = ~q[r];   // exact value recovery
      }
    }

    // ---- land staged h into LDS, wave-private column range ----
    #pragma unroll
    for (int r = 0; r < 32; ++r)
      *(unsigned long long*)&hlds[r][wave * 256 + lane * 4] = q[r];

    // ---- h phase: A-frags from LDS (row=m), B-frags from slab ----
    #pragma unroll
    for (int i = 0; i < 16; ++i) {
      const half8 av = *(const half8*)&hlds[m][wave * 256 + i * 16 + kh * 8];
      const half8 bf = *(const half8*)&slab[(wave * 16 + i) * 512 + lane * 8];
      C = __builtin_amdgcn_mfma_f32_32x32x16_f16(av, bf, C, 0, 0, 0);
    }

    // ---- WAR guard: all waves done reading red[] of step s-1 ----
    __syncthreads();

    // ---- reduce 4-wave partials (C/D layout: col=lane&31, row=(r&3)+8*(r>>2)+4*(lane>>5)) ----
    #pragma unroll
    for (int r = 0; r < 16; ++r) {
      const int row = (r & 3) + 8 * (r >> 2) + 4 * kh;
      red[wave][row][m] = C[r];
    }
    __syncthreads();

    const float z0 = red[0][bl][jj]      + red[1][bl][jj]      + red[2][bl][jj]      + red[3][bl][jj]      + bz0;
    const float z1 = red[0][bl][8 + jj]  + red[1][bl][8 + jj]  + red[2][bl][8 + jj]  + red[3][bl][8 + jj]  + bz1;
    const float z2 = red[0][bl][16 + jj] + red[1][bl][16 + jj] + red[2][bl][16 + jj] + red[3][bl][16 + jj] + bz2;
    const float z3 = red[0][bl][24 + jj] + red[1][bl][24 + jj] + red[2][bl][24 + jj] + red[3][bl][24 + jj] + bz3;

    const float ig = sigm(z0);
    const float fg = sigm(z1);
    const float gg = tanh_f(z2);
    const float og = sigm(z3);
    c = fg * c + ig * gg;
    const float hv = og * tanh_f(c);

    // ---- publish h_s IMMEDIATELY: one gen-tagged atomic u64 per 4 cols ----
    // No drain, no flag, no barrier: consumers verify on the data itself.
    {
      const int g = (s >> 1) & 1;
      union { _Float16 h2[2]; unsigned u; } pk;
      pk.h2[0] = (_Float16)hv;
      pk.h2[1] = (_Float16)__shfl_xor(hv, 1);          // partner col jj^1
      const unsigned other = __shfl_xor(pk.u, 2);      // cols (jj|2), (jj|2)^1
      if ((t & 3) == 0) {
        unsigned long long qq = (unsigned long long)pk.u
                              | ((unsigned long long)other << 32);
        if (g) qq = ~qq;
        _Float16* hdst = (s & 1) ? hb1 : hb0;
        __hip_atomic_store((unsigned long long*)(hdst + (size_t)bG * H_ + jG), qq,
                           __ATOMIC_RELAXED, __HIP_MEMORY_SCOPE_AGENT);
      }
    }

    // ---- deferred outputs, off the exchange critical path ----
    __builtin_nontemporal_store(hv, &out[((size_t)bG * T_ + s) * H_ + jG]);
    if (s == len - 1) {
      __builtin_nontemporal_store(c,  &finc[bG * H_ + jG]);
      __builtin_nontemporal_store(hv, &finh[bG * H_ + jG]);
    }

    // ---- prefetch x for step s+1 ----
    if (XF16 && (s + 1 < T_)) {
      const _Float16* xs = xbase + (size_t)(s + 1) * D_;
      #pragma unroll
      for (int i = 0; i < 16; ++i)
        xa[i] = *(const half8*)(xs + (wave * 16 + i) * 16);
    }
  }
}

// ---------------- host ----------------
extern "C" void kernel_launch(void* const* d_in, const int* in_sizes, int n_in,
                              void* d_out, int out_size, void* d_ws, size_t ws_size,
                              hipStream_t stream) {
  const float* x32    = (const float*)d_in[0];
  const int*   lens   = (const int*)  d_in[1];
  const float* init_c = (const float*)d_in[2];
  const float* init_h = (const float*)d_in[3];
  const float* Wi     = (const float*)d_in[4];
  const float* Wh     = (const float*)d_in[5];
  const float* bias   = (const float*)d_in[6];

  float* out   = (float*)d_out;
  float* fin_c = out + (size_t)B_ * T_ * H_;
  float* fin_h = fin_c + (size_t)B_ * H_;

  char* ws = (char*)d_ws;
  _Float16*  hb0   = (_Float16*)(ws + 16384);          // 128 KB
  _Float16*  hb1   = hb0 + (size_t)B_ * H_;            // 128 KB
  _Float16*  xf16  = (_Float16*)(ws + (1u << 20));     // 64 MB

  const size_t need_big = (1u << 20) + sizeof(_Float16) * (size_t)B_ * T_ * D_;

  k_prep_misc<<<256, 256, 0, stream>>>(init_h, (unsigned short*)hb0,
                                       (unsigned short*)hb1);
  if (ws_size >= need_big) {
    k_prep_x<<<16384, 256, 0, stream>>>(x32, xf16);
    k_lstm<true><<<256, 256, 0, stream>>>(x32, xf16, lens, init_c, Wi, Wh, bias,
                                          hb0, hb1, out, fin_c, fin_h);
  } else {
    k_lstm<false><<<256, 256, 0, stream>>>(x32, xf16, lens, init_c, Wi, Wh, bias,
                                           hb0, hb1, out, fin_c, fin_h);
  }
}

// Round 5
// 2813.940 us; speedup vs baseline: 1.0266x; 1.0266x over previous
//
#include <hip/hip_runtime.h>

#define B_ 64
#define T_ 512
#define D_ 1024
#define H_ 1024

typedef _Float16 half8 __attribute__((ext_vector_type(8)));
typedef float floatx16 __attribute__((ext_vector_type(16)));

__device__ __forceinline__ float sigm(float x)   { return 1.f / (1.f + __expf(-x)); }
__device__ __forceinline__ float tanh_f(float x) { return 1.f - 2.f / (1.f + __expf(2.f * x)); }

// ---------------- prep: inputs fp32 -> f16 (8 elems / thread) ----------------
__global__ void k_prep_x(const float* __restrict__ x, _Float16* __restrict__ xf) {
  int i = blockIdx.x * blockDim.x + threadIdx.x;   // 0 .. 4194303
  const float4* p = (const float4*)x + (size_t)i * 2;
  float4 a = p[0], b = p[1];
  half8 v;
  v[0]=(_Float16)a.x; v[1]=(_Float16)a.y; v[2]=(_Float16)a.z; v[3]=(_Float16)a.w;
  v[4]=(_Float16)b.x; v[5]=(_Float16)b.y; v[6]=(_Float16)b.z; v[7]=(_Float16)b.w;
  ((half8*)xf)[i] = v;
}

// ---------------- prep: h_{-1} = init_h (f16), zero flags ----------------
__global__ void k_prep_misc(const float* __restrict__ init_h,
                            _Float16* __restrict__ hb1, int* __restrict__ flags) {
  int i = blockIdx.x * blockDim.x + threadIdx.x;   // grid 256x256 = 65536
  hb1[i] = (_Float16)init_h[i];
  if (i < 4096) flags[i] = 0;
}

// ---------------- persistent LSTM kernel ----------------
// 256 WGs (1/CU), 256 threads (4 waves). WG w: batch-half bh=w>>7, col-chunk jc=w&127
// (8 hidden cols -> 32 z-cols {gate*H + jc*8+jj}).
//
// R2-proven flag protocol (no fences, minimal poll bytes):
//   writers: packed relaxed AGENT atomic u64 stores (write-through to LLC)
//            -> __syncthreads (drains vmcnt = LLC acks) -> flag relaxed store.
//   readers: per-wave poll of its own 32 producer flags (lanes 0..31; 128 B/iter),
//            then lane-contiguous u64 agent atomic loads staged via LDS transpose.
// THIS ROUND: keep all VMEM that is NOT on the exchange path (out stores,
// x prefetch) issued mid-iteration so vmcnt is drained by the next poll
// (vmcnt retires in-order; anything issued just before a poll stalls it).
template <bool XF16>
__launch_bounds__(256, 1)
__global__ void k_lstm(const float* __restrict__ x32, const _Float16* __restrict__ xf,
                       const int* __restrict__ lengths, const float* __restrict__ init_c,
                       const float* __restrict__ Wi, const float* __restrict__ Wh,
                       const float* __restrict__ bias,
                       _Float16* __restrict__ hb0, _Float16* __restrict__ hb1,
                       int* __restrict__ flags,
                       float* __restrict__ out, float* __restrict__ finc,
                       float* __restrict__ finh)
{
  __shared__ _Float16 slab[32768];       // 64 KB: Wh slice, B-frag order
  __shared__ _Float16 hlds[32][1028];    // 64.3 KB: staged h, +4 halfs pad (2-way banks)
  __shared__ float red[4][32][40];       // 20 KB: wave partials, stride 40

  const int w    = blockIdx.x;
  const int bh   = w >> 7;
  const int jc   = w & 127;
  const int t    = threadIdx.x;
  const int wave = t >> 6;
  const int lane = t & 63;
  const int m    = lane & 31;
  const int kh   = lane >> 5;

  const int gate = m >> 3;
  const int col  = gate * H_ + jc * 8 + (m & 7);

  // ---- one-time: Wh slice -> LDS slab (f16, B-fragment order, kb = k/16) ----
  for (int kbb = 0; kbb < 16; ++kbb) {
    const int kb = kbb * 4 + wave;
    const int kc = kb * 16 + kh * 8;
    half8 v;
    #pragma unroll
    for (int j = 0; j < 8; ++j)
      v[j] = (_Float16)Wh[(size_t)(kc + j) * 4096 + col];
    *(half8*)&slab[kb * 512 + lane * 8] = v;
  }

  // ---- one-time: Wi slice -> 64 permanent VGPRs (B-fragment order) ----
  half8 wia[16];
  #pragma unroll
  for (int i = 0; i < 16; ++i) {
    const int kc = (wave * 16 + i) * 16 + kh * 8;
    half8 v;
    #pragma unroll
    for (int j = 0; j < 8; ++j)
      v[j] = (_Float16)Wi[(size_t)(kc + j) * 4096 + col];
    wia[i] = v;
  }

  // ---- per-thread gate-phase ids: one (batch, hidden-col) pair ----
  const int bl = t >> 3, jj = t & 7;
  const int bG = bh * 32 + bl;
  const int jG = jc * 8 + jj;
  float c = init_c[bG * H_ + jG];
  const int len = lengths[bG];
  const float bz0 = bias[0 * H_ + jG];
  const float bz1 = bias[1 * H_ + jG];
  const float bz2 = bias[2 * H_ + jG];
  const float bz3 = bias[3 * H_ + jG];

  const int bA = bh * 32 + m;                         // A-fragment row (batch)
  const _Float16* xbase   = XF16 ? (xf + (size_t)bA * T_ * D_ + kh * 8) : (const _Float16*)0;
  const float*    xbase32 = x32 + (size_t)bA * T_ * D_ + kh * 8;

  int* myflag_w = flags + (w << 4);                             // flags padded to 64 B
  int* pollflag = flags + ((bh * 128 + wave * 32 + m) << 4);    // wave's own 32 producers

  __syncthreads();

  // ---- x fragment registers, prefetched one step ahead (64 VGPRs) ----
  half8 xa[16];
  if (XF16) {
    const _Float16* xs = xbase;   // s = 0
    #pragma unroll
    for (int i = 0; i < 16; ++i)
      xa[i] = *(const half8*)(xs + (wave * 16 + i) * 16);
  }

  float hv_prev = 0.f;     // out[s-1], flushed mid-iteration s
  float cfin = 0.f, hfin = 0.f;

  for (int s = 0; s < T_; ++s) {
    // ---- wait for h_{s-1}: each wave polls only ITS 32 producers (128 B/iter) ----
    if (lane < 32) {
      int spin = 0;
      while (__hip_atomic_load(pollflag, __ATOMIC_RELAXED, __HIP_MEMORY_SCOPE_AGENT) < s) {
        __builtin_amdgcn_s_sleep(1);
        if (++spin > (1 << 22)) break;   // safety valve against deadlock-hang
      }
    }

    // ---- issue coalesced h staging loads: lane-contiguous u64, LLC-served ----
    const _Float16* hsrc = (s & 1) ? hb0 : hb1;   // h_{s-1} buffer
    const unsigned long long* hq =
        (const unsigned long long*)hsrc + (size_t)bh * 8192;   // bh*32*1024 halfs / 4
    unsigned long long q[32];
    #pragma unroll
    for (int r = 0; r < 32; ++r)
      q[r] = __hip_atomic_load(hq + r * 256 + wave * 64 + lane,
                               __ATOMIC_RELAXED, __HIP_MEMORY_SCOPE_AGENT);

    // ---- x phase (pure-register MFMA; overlaps the h staging-load latency) ----
    floatx16 C;
    #pragma unroll
    for (int r = 0; r < 16; ++r) C[r] = 0.f;
    if (XF16) {
      #pragma unroll
      for (int i = 0; i < 16; ++i)
        C = __builtin_amdgcn_mfma_f32_32x32x16_f16(xa[i], wia[i], C, 0, 0, 0);
    } else {
      const float* xs = xbase32 + (size_t)s * D_;
      #pragma unroll
      for (int i = 0; i < 16; ++i) {
        const float4* p = (const float4*)(xs + (wave * 16 + i) * 16);
        float4 u0 = p[0], u1 = p[1];
        half8 v;
        v[0]=(_Float16)u0.x; v[1]=(_Float16)u0.y; v[2]=(_Float16)u0.z; v[3]=(_Float16)u0.w;
        v[4]=(_Float16)u1.x; v[5]=(_Float16)u1.y; v[6]=(_Float16)u1.z; v[7]=(_Float16)u1.w;
        C = __builtin_amdgcn_mfma_f32_32x32x16_f16(v, wia[i], C, 0, 0, 0);
      }
    }

    // ---- mid-iteration VMEM (drains long before the NEXT poll) ----
    if (s > 0)
      __builtin_nontemporal_store(hv_prev, &out[((size_t)bG * T_ + (s - 1)) * H_ + jG]);
    if (XF16 && (s + 1 < T_)) {
      const _Float16* xs = xbase + (size_t)(s + 1) * D_;
      #pragma unroll
      for (int i = 0; i < 16; ++i)
        xa[i] = *(const half8*)(xs + (wave * 16 + i) * 16);
    }

    // ---- land staged h into LDS (waits only the h loads; x/out are newer) ----
    #pragma unroll
    for (int r = 0; r < 32; ++r)
      *(unsigned long long*)&hlds[r][wave * 256 + lane * 4] = q[r];

    // ---- h phase: A-frags from LDS (row=m), B-frags from slab ----
    #pragma unroll
    for (int i = 0; i < 16; ++i) {
      const half8 av = *(const half8*)&hlds[m][wave * 256 + i * 16 + kh * 8];
      const half8 bf = *(const half8*)&slab[(wave * 16 + i) * 512 + lane * 8];
      C = __builtin_amdgcn_mfma_f32_32x32x16_f16(av, bf, C, 0, 0, 0);
    }

    // ---- reduce 4-wave partials (C/D layout: col=lane&31, row=(r&3)+8*(r>>2)+4*(lane>>5)) ----
    #pragma unroll
    for (int r = 0; r < 16; ++r) {
      const int row = (r & 3) + 8 * (r >> 2) + 4 * kh;
      red[wave][row][m] = C[r];
    }
    __syncthreads();

    const float z0 = red[0][bl][jj]      + red[1][bl][jj]      + red[2][bl][jj]      + red[3][bl][jj]      + bz0;
    const float z1 = red[0][bl][8 + jj]  + red[1][bl][8 + jj]  + red[2][bl][8 + jj]  + red[3][bl][8 + jj]  + bz1;
    const float z2 = red[0][bl][16 + jj] + red[1][bl][16 + jj] + red[2][bl][16 + jj] + red[3][bl][16 + jj] + bz2;
    const float z3 = red[0][bl][24 + jj] + red[1][bl][24 + jj] + red[2][bl][24 + jj] + red[3][bl][24 + jj] + bz3;

    const float ig = sigm(z0);
    const float fg = sigm(z1);
    const float gg = tanh_f(z2);
    const float og = sigm(z3);
    c = fg * c + ig * gg;
    const float hv = og * tanh_f(c);

    // ---- publish h_s: one packed atomic u64 per 4 cols (64 stores/WG) ----
    {
      union { _Float16 h2[2]; unsigned u; } pk;
      pk.h2[0] = (_Float16)hv;
      pk.h2[1] = (_Float16)__shfl_xor(hv, 1);          // partner col jj^1
      const unsigned other = __shfl_xor(pk.u, 2);      // cols (jj|2), (jj|2)^1
      if ((t & 3) == 0) {
        const unsigned long long qq = (unsigned long long)pk.u
                                    | ((unsigned long long)other << 32);
        _Float16* hdst = (s & 1) ? hb1 : hb0;
        __hip_atomic_store((unsigned long long*)(hdst + (size_t)bG * H_ + jG), qq,
                           __ATOMIC_RELAXED, __HIP_MEMORY_SCOPE_AGENT);
      }
    }

    // __syncthreads drains vmcnt(0) for every thread (publish stores LLC-acked)
    // before thread 0 publishes the flag. Also closes the red[] WAR window.
    __syncthreads();
    if (t == 0)
      __hip_atomic_store(myflag_w, s + 1, __ATOMIC_RELAXED, __HIP_MEMORY_SCOPE_AGENT);

    // ---- defer outputs to the next iteration / epilogue ----
    hv_prev = hv;
    if (s == len - 1) { cfin = c; hfin = hv; }
  }

  // ---- epilogue: tail out store + finals (off the exchange path entirely) ----
  __builtin_nontemporal_store(hv_prev, &out[((size_t)bG * T_ + (T_ - 1)) * H_ + jG]);
  __builtin_nontemporal_store(cfin, &finc[bG * H_ + jG]);
  __builtin_nontemporal_store(hfin, &finh[bG * H_ + jG]);
}

// ---------------- host ----------------
extern "C" void kernel_launch(void* const* d_in, const int* in_sizes, int n_in,
                              void* d_out, int out_size, void* d_ws, size_t ws_size,
                              hipStream_t stream) {
  const float* x32    = (const float*)d_in[0];
  const int*   lens   = (const int*)  d_in[1];
  const float* init_c = (const float*)d_in[2];
  const float* init_h = (const float*)d_in[3];
  const float* Wi     = (const float*)d_in[4];
  const float* Wh     = (const float*)d_in[5];
  const float* bias   = (const float*)d_in[6];

  float* out   = (float*)d_out;
  float* fin_c = out + (size_t)B_ * T_ * H_;
  float* fin_h = fin_c + (size_t)B_ * H_;

  char* ws = (char*)d_ws;
  int*       flags = (int*)ws;                         // 16 KB (256 flags, 64-B padded)
  _Float16*  hb0   = (_Float16*)(ws + 16384);          // 128 KB
  _Float16*  hb1   = hb0 + (size_t)B_ * H_;            // 128 KB
  _Float16*  xf16  = (_Float16*)(ws + (1u << 20));     // 64 MB

  const size_t need_big = (1u << 20) + sizeof(_Float16) * (size_t)B_ * T_ * D_;

  k_prep_misc<<<256, 256, 0, stream>>>(init_h, hb1, flags);
  if (ws_size >= need_big) {
    k_prep_x<<<16384, 256, 0, stream>>>(x32, xf16);
    k_lstm<true><<<256, 256, 0, stream>>>(x32, xf16, lens, init_c, Wi, Wh, bias,
                                          hb0, hb1, flags, out, fin_c, fin_h);
  } else {
    k_lstm<false><<<256, 256, 0, stream>>>(x32, xf16, lens, init_c, Wi, Wh, bias,
                                           hb0, hb1, flags, out, fin_c, fin_h);
  }
}